// Round 7
// baseline (3043.952 us; speedup 1.0000x reference)
//
#include <hip/hip_runtime.h>

#define SEQ 12

typedef __attribute__((ext_vector_type(8))) short bf16x8;   // 8 bf16 bit patterns (4 VGPRs)
typedef __attribute__((ext_vector_type(4))) float f32x4;
typedef __attribute__((ext_vector_type(4))) unsigned short us4;

__device__ __forceinline__ unsigned short f2bf(float x) {
    unsigned u = __builtin_bit_cast(unsigned, x);
    u += 0x7fffu + ((u >> 16) & 1u);            // round-to-nearest-even
    return (unsigned short)(u >> 16);
}
__device__ __forceinline__ float bf2f(unsigned short h) {
    unsigned u = ((unsigned)h) << 16;
    return __builtin_bit_cast(float, u);
}
// native-rate activations (r7): v_rcp_f32 + v_exp_f32, inf-safe at both tails.
__device__ __forceinline__ float sigf(float x) {
    return __builtin_amdgcn_rcpf(1.0f + __builtin_amdgcn_exp2f(-1.4426950408889634f * x));
}
__device__ __forceinline__ float tanhf_(float x) {
    return 1.0f - 2.0f * __builtin_amdgcn_rcpf(1.0f + __builtin_amdgcn_exp2f(2.8853900817779268f * x));
}

// ---------------- weight pack kernel (layout UNCHANGED) ----------------
// d_ws layout (ushort), SINGLE copy (640 KB):
//   [0,65536)        PRE0 = bf16(W_ih_l0[:, :128])  K=128
//   [65536,131072)   INIT = bf16(W_init [:, :128])  K=128
//   [131072,196608)   L0  = bf16(W_hh_l0)           K=128
//   [196608,327680)   L1  = bf16([W_ih_l1|W_hh_l1]) K=256
// fragment order: chunk = ((w8*4+G)*KK + kk) covers cols G*128 + w8*16;
// within chunk: lane*8+j, n = G*128 + w8*16 + (lane&15), k = kk*32 + (lane>>4)*8 + j
__global__ void pack_w(const float* __restrict__ Winit, const float* __restrict__ Wihl0,
                       const float* __restrict__ Whhl0, const float* __restrict__ Wihl1,
                       const float* __restrict__ Whhl1, unsigned short* __restrict__ pk,
                       int ncopy) {
    int id = blockIdx.x * 256 + threadIdx.x;
    if (id >= 327680) return;
    float v;
    if (id < 131072) {                       // PRE0 / INIT (stride 129, KK=4)
        int e = id & 65535;
        int c = e >> 9, r = e & 511;
        int lane = r >> 3, j = r & 7;
        int kk = c & 3, G = (c >> 2) & 3, w = c >> 4;
        int n = G * 128 + w * 16 + (lane & 15);
        int k = kk * 32 + (lane >> 4) * 8 + j;
        const float* W = (id >> 16) ? Winit : Wihl0;
        v = W[n * 129 + k];
    } else if (id < 196608) {                // L0 (stride 128, KK=4)
        int e = id - 131072;
        int c = e >> 9, r = e & 511;
        int lane = r >> 3, j = r & 7;
        int kk = c & 3, G = (c >> 2) & 3, w = c >> 4;
        int n = G * 128 + w * 16 + (lane & 15);
        int k = kk * 32 + (lane >> 4) * 8 + j;
        v = Whhl0[n * 128 + k];
    } else {                                 // L1 (K=256, KK=8)
        int e = id - 196608;
        int c = e >> 9, r = e & 511;
        int lane = r >> 3, j = r & 7;
        int kk = c & 7, G = (c >> 3) & 3, w = c >> 5;
        int n = G * 128 + w * 16 + (lane & 15);
        int k = kk * 32 + (lane >> 4) * 8 + j;
        v = (k < 128) ? Wihl1[n * 128 + k] : Whhl1[n * 128 + (k - 128)];
    }
    unsigned short hv = f2bf(v);
    for (int cpy = 0; cpy < ncopy; ++cpy) pk[cpy * 327680 + id] = hv;
}

// r12 macros: 4 waves, wave w owns cols [32w,32w+32) as halves u=0,1 (w8=2w+u).
// A-ring ar[2][4] (1 group ahead), B-ring bb[2][8] (2 groups ahead).
#define LOAD_A(slot, hb, kkl) do { _Pragma("unroll") \
    for (int mt = 0; mt < 4; ++mt) \
        ar[slot][mt] = *(const bf16x8*)&(hb)[(mt * 16 + nq) * 128 + ((((kkl) * 4 + quad) ^ nq) << 3)]; \
    } while (0)
#define LOAD_B(slot, base, KK, kk) do { _Pragma("unroll") \
    for (int u = 0; u < 2; ++u) { _Pragma("unroll") \
        for (int G = 0; G < 4; ++G) \
            bb[slot][u * 4 + G] = *(const bf16x8*)&(base)[(((w * 2 + u) * 4 + G) * (KK) + (kk)) * 512 + lane * 8]; } \
    } while (0)
#define MFMA_ACC(sa, sb) do { _Pragma("unroll") \
    for (int mt = 0; mt < 4; ++mt) { _Pragma("unroll") \
        for (int u = 0; u < 2; ++u) { _Pragma("unroll") \
            for (int G = 0; G < 4; ++G) \
                acc[mt][u][G] = __builtin_amdgcn_mfma_f32_16x16x32_bf16(ar[sa][mt], bb[sb][u * 4 + G], acc[mt][u][G], 0, 0, 0); } } \
    } while (0)
#define MFMA_IPRE(sa, sb) do { _Pragma("unroll") \
    for (int mt = 0; mt < 4; ++mt) { _Pragma("unroll") \
        for (int u = 0; u < 2; ++u) { _Pragma("unroll") \
            for (int G = 0; G < 4; ++G) \
                acc[mt][u][G] = __builtin_amdgcn_mfma_f32_16x16x32_bf16(ar[sa][mt], bb[sb][u * 4 + G], pre0[mt][u][G], 0, 0, 0); } } \
    } while (0)
#define MFMA_IBL(sa, sb) do { _Pragma("unroll") \
    for (int mt = 0; mt < 4; ++mt) { _Pragma("unroll") \
        for (int u = 0; u < 2; ++u) { _Pragma("unroll") \
            for (int G = 0; G < 4; ++G) \
                acc[mt][u][G] = __builtin_amdgcn_mfma_f32_16x16x32_bf16(ar[sa][mt], bb[sb][u * 4 + G], blv[u][G], 0, 0, 0); } } \
    } while (0)

// ---------------- fused decoder kernel ----------------
// r12: 256 thr (4 waves), Mt=64 (same tile/traffic as r11, half the waves).
// 1 wave/SIMD => 512 unified regs/wave: pre0(128) + acc(128) + c1/c2 f32(64)
// + B-ring(64) + A-ring(32) + blv(32) ~ 480 regs, ALL resident -> no scratch.
// The 512-thr variants could never fit (2 waves/SIMD => 256-reg cap) and spilled
// ~0.65 GB/dispatch, whose L2 churn evicted the weight set (3.7 GB FETCH).
// acc init is free via MFMA C-in (pre0 for L0 kk0, bl1 broadcast for L1 kk0).
__global__ __launch_bounds__(256) __attribute__((amdgpu_waves_per_eu(1, 1)))
void traj_main(const float* __restrict__ fused, const float* __restrict__ intent,
               const float* __restrict__ binit,
               const float* __restrict__ Winit, const float* __restrict__ Wihl0,
               const float* __restrict__ bihl0, const float* __restrict__ bhhl0,
               const float* __restrict__ bihl1, const float* __restrict__ bhhl1,
               const float* __restrict__ Wout, const float* __restrict__ bout,
               const unsigned short* __restrict__ pk,
               float* __restrict__ out, int Bsz) {
    // phase-A x-tiles; after phase A re-purposed as bf16 c0 staging
    __shared__ __align__(16) unsigned char s_u[32768];
    unsigned short* s_x  = (unsigned short*)s_u;            // 64x128 bf16 (16 KB)
    unsigned short* s_xi = (unsigned short*)(s_u + 16384);  // 64x128 bf16 (16 KB)
    unsigned short* s_c1 = (unsigned short*)s_u;            // [64][128] bf16 c0 l0
    unsigned short* s_c2 = (unsigned short*)(s_u + 16384);  // [64][128] bf16 c0 l1
    __shared__ __align__(16) unsigned short s_h1[2][64 * 128];   // h1 double buffer
    __shared__ __align__(16) unsigned short s_h2[2][64 * 128];   // h2 double buffer
    __shared__ float s_wo[256];                                  // W_out (2x128)
    __shared__ float s_out[64 * 24];                             // per-step outputs

    const int tid = threadIdx.x;
    const int lane = tid & 63;
    const int w = tid >> 6;          // wave 0..3
    const int nq = lane & 15;
    const int quad = lane >> 4;
    const int m0 = blockIdx.x * 64;
    const int Bh = Bsz >> 1;

    const unsigned short* pkPRE = pk;
    const unsigned short* pkINI = pk + 65536;
    const unsigned short* pkL0  = pk + 131072;
    const unsigned short* pkL1  = pk + 196608;

    s_wo[tid] = Wout[tid];
    const float bo2 = bout[(tid >> 1) & 1];    // head: oc = bit1 of tid

    // per-lane column constants (n = G*128 + w*32 + u*16 + nq)
    float bpre[2][4], bl1[2][4], wcp[2][4], wci[2][4], bini[2][4];
#pragma unroll
    for (int u = 0; u < 2; ++u)
#pragma unroll
        for (int G = 0; G < 4; ++G) {
            int n = G * 128 + w * 32 + u * 16 + nq;
            bpre[u][G] = bihl0[n] + bhhl0[n];
            bl1[u][G]  = bihl1[n] + bhhl1[n];
            wcp[u][G]  = Wihl0[n * 129 + 128];    // intent column of W_ih_l0
            wci[u][G]  = Winit[n * 129 + 128];    // intent column of W_init
            bini[u][G] = binit[n];
        }

    // ---- stage tiles as bf16 (swizzled A-layout): 64 x-rows + 64 init-x rows
#pragma unroll
    for (int it = 0; it < 16; ++it) {
        int f = it * 256 + tid;
        int row = f >> 5, fc = f & 31;
        int g = (row < 64) ? (m0 + row)
                           : ((row < 96) ? ((m0 >> 1) + (row - 64))
                                         : (Bh + (m0 >> 1) + (row - 96)));
        f32x4 v = *(const f32x4*)(fused + g * 128 + fc * 4);
        us4 u;
#pragma unroll
        for (int j = 0; j < 4; ++j) u[j] = f2bf(v[j]);
        int m = row & 63;
        int cp = (fc >> 1) ^ (m & 15);
        unsigned short* buf = (row < 64) ? s_x : s_xi;
        *(us4*)&buf[m * 128 + cp * 8 + (fc & 1) * 4] = u;
    }
    __syncthreads();

    // ---- phase A: pre0 = x@Wihl0^T (+b,+intent), initacc = x'@Winit^T (+b,+intent)
    f32x4 pre0[4][2][4], acc2[4][2][4];
#pragma unroll
    for (int mt = 0; mt < 4; ++mt)
#pragma unroll
        for (int u = 0; u < 2; ++u)
#pragma unroll
            for (int G = 0; G < 4; ++G) {
                pre0[mt][u][G] = (f32x4){0.f, 0.f, 0.f, 0.f};
                acc2[mt][u][G] = (f32x4){0.f, 0.f, 0.f, 0.f};
            }
#pragma unroll
    for (int kk = 0; kk < 4; ++kk) {
        bf16x8 av[4], a2[4], bv[8], b2[8];
#pragma unroll
        for (int mt = 0; mt < 4; ++mt) {
            int idx = (mt * 16 + nq) * 128 + (((kk * 4 + quad) ^ nq) << 3);
            av[mt] = *(const bf16x8*)&s_x[idx];
            a2[mt] = *(const bf16x8*)&s_xi[idx];
        }
#pragma unroll
        for (int u = 0; u < 2; ++u)
#pragma unroll
            for (int G = 0; G < 4; ++G) {
                int off = (((w * 2 + u) * 4 + G) * 4 + kk) * 512 + lane * 8;
                bv[u * 4 + G] = *(const bf16x8*)&pkPRE[off];
                b2[u * 4 + G] = *(const bf16x8*)&pkINI[off];
            }
#pragma unroll
        for (int mt = 0; mt < 4; ++mt)
#pragma unroll
            for (int u = 0; u < 2; ++u)
#pragma unroll
                for (int G = 0; G < 4; ++G) {
                    pre0[mt][u][G] = __builtin_amdgcn_mfma_f32_16x16x32_bf16(av[mt], bv[u * 4 + G], pre0[mt][u][G], 0, 0, 0);
                    acc2[mt][u][G] = __builtin_amdgcn_mfma_f32_16x16x32_bf16(a2[mt], b2[u * 4 + G], acc2[mt][u][G], 0, 0, 0);
                }
    }
#pragma unroll
    for (int mt = 0; mt < 4; ++mt)
#pragma unroll
        for (int r = 0; r < 4; ++r) {
            int ml = mt * 16 + quad * 4 + r;
            float iv = intent[m0 + ml];
            int grow = (mt < 2) ? ((m0 >> 1) + ml) : (Bh + (m0 >> 1) + (ml - 32));
            float iv2 = intent[grow];
#pragma unroll
            for (int u = 0; u < 2; ++u)
#pragma unroll
                for (int G = 0; G < 4; ++G) {
                    pre0[mt][u][G][r] += bpre[u][G] + iv * wcp[u][G];
                    acc2[mt][u][G][r] += bini[u][G] + iv2 * wci[u][G];
                }
        }
    __syncthreads();   // x-tile reads complete; s_u becomes c0 staging

    // ---- unpack init (torch-faithful flat reshape of [B,2H]->(2,B,H)):
    // init row ri: layer = ri>>5, ril = ri&31, sample ml = 2*ril + (G&1);
    // G0/G1 -> h (swizzled bf16), G2/G3 -> c (plain [ml][kq] bf16 staging).
    {
#pragma unroll
        for (int mt = 0; mt < 4; ++mt)
#pragma unroll
            for (int r = 0; r < 4; ++r) {
                int ri = mt * 16 + quad * 4 + r;
                int layer = mt >> 1;
                int ril = ri & 31;
#pragma unroll
                for (int u = 0; u < 2; ++u) {
                    int kq = w * 32 + u * 16 + nq;
                    int kc = kq >> 3, klo = kq & 7;
#pragma unroll
                    for (int G = 0; G < 4; ++G) {
                        int ml = 2 * ril + (G & 1);
                        unsigned short hv = f2bf(acc2[mt][u][G][r]);
                        if (G < 2) {
                            unsigned short* hb = layer ? s_h2[0] : s_h1[0];
                            hb[ml * 128 + ((kc ^ (ml & 15)) << 3) + klo] = hv;
                        } else {
                            unsigned short* cb = layer ? s_c2 : s_c1;
                            cb[ml * 128 + kq] = hv;
                        }
                    }
                }
            }
    }
    __syncthreads();   // h + c staging visible

    // ---- load c into f32 registers (resident for all 12 steps)
    f32x4 c1v[4][2], c2v[4][2];
#pragma unroll
    for (int mt = 0; mt < 4; ++mt)
#pragma unroll
        for (int u = 0; u < 2; ++u) {
            int kq = w * 32 + u * 16 + nq;
#pragma unroll
            for (int r = 0; r < 4; ++r) {
                int ml = mt * 16 + quad * 4 + r;
                c1v[mt][u][r] = bf2f(s_c1[ml * 128 + kq]);
                c2v[mt][u][r] = bf2f(s_c2[ml * 128 + kq]);
            }
        }

    // bl1 broadcast vectors for L1 acc init via MFMA C-in
    f32x4 blv[2][4];
#pragma unroll
    for (int u = 0; u < 2; ++u)
#pragma unroll
        for (int G = 0; G < 4; ++G)
            blv[u][G] = (f32x4){bl1[u][G], bl1[u][G], bl1[u][G], bl1[u][G]};

    // ---- prefetch warm-up: B 2 groups ahead, A 1 group ahead
    bf16x8 bb[2][8], ar[2][4];
    LOAD_B(0, pkL0, 4, 0);
    LOAD_B(1, pkL0, 4, 1);
    LOAD_A(0, s_h1[0], 0);

    // ---- 12 decode steps; 12 groups/step (L0 k0..3 from h1r, L1 k0..7 from
    // h1w|h2r), 32 MFMA/group. Per group: issue next A, MFMA, refill B slot.
#pragma unroll 1
    for (int s = 0; s < SEQ; ++s) {
        const int p = s & 1;
        const unsigned short* h1r = s_h1[p];
        unsigned short*       h1w = s_h1[1 - p];
        const unsigned short* h2r = s_h2[p];
        unsigned short*       h2w = s_h2[1 - p];

        f32x4 acc[4][2][4];
        // layer0: acc = pre0 + h1 @ Whhl0^T  (K=128)
        LOAD_A(1, h1r, 1); MFMA_IPRE(0, 0); LOAD_B(0, pkL0, 4, 2);
        LOAD_A(0, h1r, 2); MFMA_ACC(1, 1);  LOAD_B(1, pkL0, 4, 3);
        LOAD_A(1, h1r, 3); MFMA_ACC(0, 0);  LOAD_B(0, pkL1, 8, 0);
                           MFMA_ACC(1, 1);  LOAD_B(1, pkL1, 8, 1);
        // pointwise layer0 (L1 k0/k1 B-loads in flight over pointwise+barrier)
#pragma unroll
        for (int mt = 0; mt < 4; ++mt)
#pragma unroll
            for (int u = 0; u < 2; ++u) {
                int kc8 = w * 4 + u * 2 + (nq >> 3);
#pragma unroll
                for (int r = 0; r < 4; ++r) {
                    float iv = acc[mt][u][0][r], fv = acc[mt][u][1][r];
                    float gv = acc[mt][u][2][r], ov = acc[mt][u][3][r];
                    float cn = sigf(fv) * c1v[mt][u][r] + sigf(iv) * tanhf_(gv);
                    float hn = sigf(ov) * tanhf_(cn);
                    c1v[mt][u][r] = cn;
                    int ml = mt * 16 + quad * 4 + r;
                    h1w[ml * 128 + ((kc8 ^ (quad * 4 + r)) << 3) + (nq & 7)] = f2bf(hn);
                }
            }
        __syncthreads();   // B1: new h1 visible
        LOAD_A(0, h1w, 0);
        // layer1: acc = bl1 + [h1_new | h2] @ [Wihl1 | Whhl1]^T  (K=256)
        LOAD_A(1, h1w, 1); MFMA_IBL(0, 0);  LOAD_B(0, pkL1, 8, 2);
        LOAD_A(0, h1w, 2); MFMA_ACC(1, 1);  LOAD_B(1, pkL1, 8, 3);
        LOAD_A(1, h1w, 3); MFMA_ACC(0, 0);  LOAD_B(0, pkL1, 8, 4);
        LOAD_A(0, h2r, 0); MFMA_ACC(1, 1);  LOAD_B(1, pkL1, 8, 5);
        LOAD_A(1, h2r, 1); MFMA_ACC(0, 0);  LOAD_B(0, pkL1, 8, 6);
        LOAD_A(0, h2r, 2); MFMA_ACC(1, 1);  LOAD_B(1, pkL1, 8, 7);
        LOAD_A(1, h2r, 3); MFMA_ACC(0, 0);  LOAD_B(0, pkL0, 4, 0);   // next L0 k0
        LOAD_A(0, h1w, 0); MFMA_ACC(1, 1);  LOAD_B(1, pkL0, 4, 1);   // next A g0 + L0 k1
        // pointwise layer1 (next-step L0 loads in flight)
#pragma unroll
        for (int mt = 0; mt < 4; ++mt)
#pragma unroll
            for (int u = 0; u < 2; ++u) {
                int kc8 = w * 4 + u * 2 + (nq >> 3);
#pragma unroll
                for (int r = 0; r < 4; ++r) {
                    float iv = acc[mt][u][0][r], fv = acc[mt][u][1][r];
                    float gv = acc[mt][u][2][r], ov = acc[mt][u][3][r];
                    float cn = sigf(fv) * c2v[mt][u][r] + sigf(iv) * tanhf_(gv);
                    float hn = sigf(ov) * tanhf_(cn);
                    c2v[mt][u][r] = cn;
                    int ml = mt * 16 + quad * 4 + r;
                    h2w[ml * 128 + ((kc8 ^ (quad * 4 + r)) << 3) + (nq & 7)] = f2bf(hn);
                }
            }
        __syncthreads();   // B2: new h2 visible
        // output head over all 256 threads: ml = tid>>2, oc = bit1, kh = bit0
        // (8 of 16 column chunks each), shfl_xor(1) combines the two halves.
        {
            int ml = tid >> 2;
            int kh = tid & 1;
            const float* wr = s_wo + ((tid >> 1) & 1) * 128;
            int mx = ml & 15;
            float sum = 0.f;
#pragma unroll
            for (int c8 = 0; c8 < 8; ++c8) {
                int c = kh * 8 + c8;
                bf16x8 hv = *(const bf16x8*)&h2w[ml * 128 + ((c ^ mx) << 3)];
                int k0 = c << 3;
#pragma unroll
                for (int j = 0; j < 8; ++j)
                    sum += bf2f((unsigned short)hv[j]) * wr[k0 + j];
            }
            sum += __shfl_xor(sum, 1);
            if (kh == 0) s_out[ml * 24 + s * 2 + ((tid >> 1) & 1)] = sum + bo2;
        }
    }
    __syncthreads();
    // single contiguous coalesced store: 64 samples x 24 floats = 6 KB
    for (int i = tid; i < 1536; i += 256) out[m0 * 24 + i] = s_out[i];
}

extern "C" void kernel_launch(void* const* d_in, const int* in_sizes, int n_in,
                              void* d_out, int out_size, void* d_ws, size_t ws_size,
                              hipStream_t stream) {
    const float* fused  = (const float*)d_in[0];
    const float* intent = (const float*)d_in[1];
    const float* Winit  = (const float*)d_in[2];
    const float* binit  = (const float*)d_in[3];
    const float* Wihl0  = (const float*)d_in[4];
    const float* Whhl0  = (const float*)d_in[5];
    const float* bihl0  = (const float*)d_in[6];
    const float* bhhl0  = (const float*)d_in[7];
    const float* Wihl1  = (const float*)d_in[8];
    const float* Whhl1  = (const float*)d_in[9];
    const float* bihl1  = (const float*)d_in[10];
    const float* bhhl1  = (const float*)d_in[11];
    const float* Wout   = (const float*)d_in[12];
    const float* bout   = (const float*)d_in[13];
    int Bsz = in_sizes[0] / 128;

    unsigned short* pkw = (unsigned short*)d_ws;   // single 640 KB copy
    pack_w<<<1280, 256, 0, stream>>>(Winit, Wihl0, Whhl0, Wihl1, Whhl1, pkw, 1);
    traj_main<<<Bsz / 64, 256, 0, stream>>>(fused, intent, binit, Winit, Wihl0, bihl0,
                                            bhhl0, bihl1, bhhl1, Wout, bout, pkw,
                                            (float*)d_out, Bsz);
}

// Round 9
// 2071.990 us; speedup vs baseline: 1.4691x; 1.4691x over previous
//
#include <hip/hip_runtime.h>

#define SEQ 12

typedef __attribute__((ext_vector_type(8))) short bf16x8;   // 8 bf16 bit patterns (4 VGPRs)
typedef __attribute__((ext_vector_type(4))) float f32x4;
typedef __attribute__((ext_vector_type(4))) unsigned short us4;

__device__ __forceinline__ unsigned short f2bf(float x) {
    unsigned u = __builtin_bit_cast(unsigned, x);
    u += 0x7fffu + ((u >> 16) & 1u);            // round-to-nearest-even
    return (unsigned short)(u >> 16);
}
__device__ __forceinline__ float bf2f(unsigned short h) {
    unsigned u = ((unsigned)h) << 16;
    return __builtin_bit_cast(float, u);
}
// native-rate activations (r7): v_rcp_f32 + v_exp_f32, inf-safe at both tails.
__device__ __forceinline__ float sigf(float x) {
    return __builtin_amdgcn_rcpf(1.0f + __builtin_amdgcn_exp2f(-1.4426950408889634f * x));
}
__device__ __forceinline__ float tanhf_(float x) {
    return 1.0f - 2.0f * __builtin_amdgcn_rcpf(1.0f + __builtin_amdgcn_exp2f(2.8853900817779268f * x));
}

// ---------------- weight pack kernel (layout UNCHANGED) ----------------
// d_ws layout (ushort), SINGLE copy (640 KB):
//   [0,65536)        PRE0 = bf16(W_ih_l0[:, :128])  K=128
//   [65536,131072)   INIT = bf16(W_init [:, :128])  K=128
//   [131072,196608)   L0  = bf16(W_hh_l0)           K=128
//   [196608,327680)   L1  = bf16([W_ih_l1|W_hh_l1]) K=256
// fragment order: chunk = ((w*4+G)*KK + kk), within chunk: lane*8+j,
//   n = G*128 + w*16 + (lane&15),  k = kk*32 + (lane>>4)*8 + j
__global__ void pack_w(const float* __restrict__ Winit, const float* __restrict__ Wihl0,
                       const float* __restrict__ Whhl0, const float* __restrict__ Wihl1,
                       const float* __restrict__ Whhl1, unsigned short* __restrict__ pk,
                       int ncopy) {
    int id = blockIdx.x * 256 + threadIdx.x;
    if (id >= 327680) return;
    float v;
    if (id < 131072) {                       // PRE0 / INIT (stride 129, KK=4)
        int e = id & 65535;
        int c = e >> 9, r = e & 511;
        int lane = r >> 3, j = r & 7;
        int kk = c & 3, G = (c >> 2) & 3, w = c >> 4;
        int n = G * 128 + w * 16 + (lane & 15);
        int k = kk * 32 + (lane >> 4) * 8 + j;
        const float* W = (id >> 16) ? Winit : Wihl0;
        v = W[n * 129 + k];
    } else if (id < 196608) {                // L0 (stride 128, KK=4)
        int e = id - 131072;
        int c = e >> 9, r = e & 511;
        int lane = r >> 3, j = r & 7;
        int kk = c & 3, G = (c >> 2) & 3, w = c >> 4;
        int n = G * 128 + w * 16 + (lane & 15);
        int k = kk * 32 + (lane >> 4) * 8 + j;
        v = Whhl0[n * 128 + k];
    } else {                                 // L1 (K=256, KK=8)
        int e = id - 196608;
        int c = e >> 9, r = e & 511;
        int lane = r >> 3, j = r & 7;
        int kk = c & 7, G = (c >> 3) & 3, w = c >> 5;
        int n = G * 128 + w * 16 + (lane & 15);
        int k = kk * 32 + (lane >> 4) * 8 + j;
        v = (k < 128) ? Wihl1[n * 128 + k] : Whhl1[n * 128 + (k - 128)];
    }
    unsigned short hv = f2bf(v);
    for (int cpy = 0; cpy < ncopy; ++cpy) pk[cpy * 327680 + id] = hv;
}

// per-group helpers (macros so everything stays in registers, fully unrolled)
#define LOAD_A(hb, kkl) do { _Pragma("unroll") \
    for (int mt = 0; mt < 4; ++mt) \
        a[mt] = *(const bf16x8*)&(hb)[(mt * 16 + nq) * 128 + ((((kkl) * 4 + quad) ^ nq) << 3)]; \
    } while (0)
#define LOAD_B(slot, base, KK, kk) do { _Pragma("unroll") \
    for (int G = 0; G < 4; ++G) \
        bb[slot][G] = *(const bf16x8*)&(base)[((w * 4 + G) * (KK) + (kk)) * 512 + lane * 8]; \
    } while (0)
#define MFMA_G(slot) do { _Pragma("unroll") \
    for (int mt = 0; mt < 4; ++mt) { _Pragma("unroll") \
        for (int G = 0; G < 4; ++G) \
            acc[mt][G] = __builtin_amdgcn_mfma_f32_16x16x32_bf16(a[mt], bb[slot][G], acc[mt][G], 0, 0, 0); } \
    } while (0)

// ---------------- fused decoder kernel ----------------
// block: 512 thr (8 waves), Mt=64. wave w owns hidden cols [16w,16w+16) x 4 gates.
// r6: weight prefetch ring. r7: native activations + distributed head + c f32
// in regs. r9: single weight copy. r11: pre0 partially in LDS.
// r13: FINISH the de-spill inside the 512-thr structure (r12 showed arch VGPRs
// cap at 256, so the 256-thr escape is impossible): pre0 quarters mt=2,3 BOTH
// live in LDS f32 (64 KB, chunk-major slot=(q*4+G)*512+tid -> lane-stride-16B
// conflict-free ds_read_b128); c-state returns to f32 VGPRs (r7 scheme).
// AGPR demand 112->96 (pre0 32 + acc 64), VGPR ~125 => total ~221 < 256:
// first variant whose live set provably fits the 2-waves/SIMD budget.
__global__ __launch_bounds__(512) __attribute__((amdgpu_waves_per_eu(2, 2)))
void traj_main(const float* __restrict__ fused, const float* __restrict__ intent,
               const float* __restrict__ binit,
               const float* __restrict__ Winit, const float* __restrict__ Wihl0,
               const float* __restrict__ bihl0, const float* __restrict__ bhhl0,
               const float* __restrict__ bihl1, const float* __restrict__ bhhl1,
               const float* __restrict__ Wout, const float* __restrict__ bout,
               const unsigned short* __restrict__ pk,
               float* __restrict__ out, int Bsz) {
    // 64 KB union: phase A = x-tiles (2x16 KB); after = pre0 mt=2,3 f32 (64 KB)
    __shared__ __align__(16) unsigned char s_big[65536];
    unsigned short* s_x  = (unsigned short*)s_big;            // 64x128 bf16
    unsigned short* s_xi = (unsigned short*)(s_big + 16384);  // 64x128 bf16
    f32x4*          s_pre = (f32x4*)s_big;                    // [8][512] f32x4
    __shared__ __align__(16) unsigned short s_h1[2][64 * 128];   // h1 dbuf ([1] = c1 staging pre-loop)
    __shared__ __align__(16) unsigned short s_h2[2][64 * 128];   // h2 dbuf ([1] = c2 staging pre-loop)
    __shared__ float s_wo[256];                                  // W_out (2x128)
    __shared__ float s_out[64 * 24];                             // per-step outputs

    const int tid = threadIdx.x;
    const int lane = tid & 63;
    const int w = tid >> 6;          // wave 0..7
    const int nq = lane & 15;
    const int quad = lane >> 4;
    const int m0 = blockIdx.x * 64;
    const int Bh = Bsz >> 1;

    const unsigned short* pkPRE = pk;
    const unsigned short* pkINI = pk + 65536;
    const unsigned short* pkL0  = pk + 131072;
    const unsigned short* pkL1  = pk + 196608;

    if (tid < 256) s_wo[tid] = Wout[tid];
    const float bo2 = bout[(tid >> 2) & 1];    // head: oc = bit2 of tid

    // per-lane column constants (n = G*128 + 16w + nq)
    float bpre[4], bl1[4], wcp[4], wci[4], bini[4];
#pragma unroll
    for (int G = 0; G < 4; ++G) {
        int n = G * 128 + w * 16 + nq;
        bpre[G] = bihl0[n] + bhhl0[n];
        bl1[G]  = bihl1[n] + bhhl1[n];
        wcp[G]  = Wihl0[n * 129 + 128];    // intent column of W_ih_l0
        wci[G]  = Winit[n * 129 + 128];    // intent column of W_init
        bini[G] = binit[n];
    }

    // ---- stage tiles as bf16 (swizzled A-layout)
#pragma unroll
    for (int it = 0; it < 8; ++it) {
        int f = it * 512 + tid;
        int row = f >> 5, fc = f & 31;
        int g = (row < 64) ? (m0 + row)
                           : ((row < 96) ? ((m0 >> 1) + (row - 64))
                                         : (Bh + (m0 >> 1) + (row - 96)));
        f32x4 v = *(const f32x4*)(fused + g * 128 + fc * 4);
        us4 u;
#pragma unroll
        for (int j = 0; j < 4; ++j) u[j] = f2bf(v[j]);
        int m = row & 63;
        int cp = (fc >> 1) ^ (m & 15);
        unsigned short* buf = (row < 64) ? s_x : s_xi;
        *(us4*)&buf[m * 128 + cp * 8 + (fc & 1) * 4] = u;
    }
    __syncthreads();

    // ---- phase A: pre0 = x@Wihl0^T (+b,+intent), initacc = x'@Winit^T (+b,+intent)
    // pre0 mt 0,1 stay in AGPRs; mt 2,3 go to s_pre after bias-add.
    f32x4 pre0[2][4], pre23[2][4], acc2[4][4];
#pragma unroll
    for (int G = 0; G < 4; ++G) {
#pragma unroll
        for (int q = 0; q < 2; ++q) {
            pre0[q][G]  = (f32x4){0.f, 0.f, 0.f, 0.f};
            pre23[q][G] = (f32x4){0.f, 0.f, 0.f, 0.f};
        }
#pragma unroll
        for (int mt = 0; mt < 4; ++mt)
            acc2[mt][G] = (f32x4){0.f, 0.f, 0.f, 0.f};
    }
#pragma unroll
    for (int kk = 0; kk < 4; ++kk) {
        bf16x8 av[4], bv[4], a2[4], b2[4];
#pragma unroll
        for (int mt = 0; mt < 4; ++mt) {
            int idx = (mt * 16 + nq) * 128 + (((kk * 4 + quad) ^ nq) << 3);
            av[mt] = *(const bf16x8*)&s_x[idx];
            a2[mt] = *(const bf16x8*)&s_xi[idx];
        }
#pragma unroll
        for (int G = 0; G < 4; ++G) {
            int off = ((w * 4 + G) * 4 + kk) * 512 + lane * 8;
            bv[G] = *(const bf16x8*)&pkPRE[off];
            b2[G] = *(const bf16x8*)&pkINI[off];
        }
#pragma unroll
        for (int mt = 0; mt < 4; ++mt)
#pragma unroll
            for (int G = 0; G < 4; ++G) {
                f32x4& pd = (mt < 2) ? pre0[mt][G] : pre23[mt - 2][G];
                pd = __builtin_amdgcn_mfma_f32_16x16x32_bf16(av[mt], bv[G], pd, 0, 0, 0);
                acc2[mt][G] = __builtin_amdgcn_mfma_f32_16x16x32_bf16(a2[mt], b2[G], acc2[mt][G], 0, 0, 0);
            }
    }
#pragma unroll
    for (int mt = 0; mt < 4; ++mt)
#pragma unroll
        for (int r = 0; r < 4; ++r) {
            int ml = mt * 16 + quad * 4 + r;
            float iv = intent[m0 + ml];
            int grow = (mt < 2) ? ((m0 >> 1) + ml) : (Bh + (m0 >> 1) + (ml - 32));
            float iv2 = intent[grow];
#pragma unroll
            for (int G = 0; G < 4; ++G) {
                f32x4& pd = (mt < 2) ? pre0[mt][G] : pre23[mt - 2][G];
                pd[r] += bpre[G] + iv * wcp[G];
                acc2[mt][G][r] += bini[G] + iv2 * wci[G];
            }
        }
    __syncthreads();   // all x-tile reads complete -> s_big can become s_pre

    // ---- write pre0 mt=2,3 to LDS (f32 exact, conflict-free chunk-major)
#pragma unroll
    for (int q = 0; q < 2; ++q)
#pragma unroll
        for (int G = 0; G < 4; ++G)
            s_pre[(q * 4 + G) * 512 + tid] = pre23[q][G];

    // ---- unpack init (torch-faithful flat reshape of [B,2H]->(2,B,H)):
    // init row r=(m>>1): G0->h even cols, G1->h odd, G2->c even, G3->c odd;
    // mt 0,1 -> layer0, mt 2,3 -> layer1. h -> s_h*[0] (swizzled, bf16);
    // c -> s_h*[1] linear [ml*128+kq] bf16 staging (read back pre-loop).
    {
        int kq = w * 16 + nq, kc = kq >> 3, klo = kq & 7;
#pragma unroll
        for (int mt = 0; mt < 4; ++mt)
#pragma unroll
            for (int r = 0; r < 4; ++r) {
                int ri = mt * 16 + quad * 4 + r;
                int layer = mt >> 1;
                int ril = ri & 31;
#pragma unroll
                for (int G = 0; G < 4; ++G) {
                    int ml = 2 * ril + (G & 1);
                    unsigned short hv = f2bf(acc2[mt][G][r]);
                    if (G < 2) {
                        unsigned short* hb = layer ? s_h2[0] : s_h1[0];
                        hb[ml * 128 + ((kc ^ (ml & 15)) << 3) + klo] = hv;
                    } else {
                        unsigned short* cb = layer ? s_h2[1] : s_h1[1];
                        cb[ml * 128 + kq] = hv;
                    }
                }
            }
    }
    __syncthreads();

    // ---- load c into f32 registers (resident for all 12 steps)
    f32x4 c1v[4], c2v[4];
    {
        int kq = w * 16 + nq;
#pragma unroll
        for (int mt = 0; mt < 4; ++mt)
#pragma unroll
            for (int r = 0; r < 4; ++r) {
                int ml = mt * 16 + quad * 4 + r;
                c1v[mt][r] = bf2f(s_h1[1][ml * 128 + kq]);
                c2v[mt][r] = bf2f(s_h2[1][ml * 128 + kq]);
            }
    }
    __syncthreads();   // c reads done before step 0 overwrites s_h*[1]

    // ---- prefetch ring warm-up: first two weight groups of step 0
    bf16x8 bb[2][4];
    LOAD_B(0, pkL0, 4, 0);
    LOAD_B(1, pkL0, 4, 1);

    // ---- 12 decode steps; ring of 12 groups/step: L0 k0..3, L1 k0..7.
    // pattern per group: MFMA(slot) then refill same slot with group 2 ahead.
#pragma unroll 1
    for (int s = 0; s < SEQ; ++s) {
        const int p = s & 1;
        const unsigned short* h1r = s_h1[p];
        unsigned short*       h1w = s_h1[1 - p];
        const unsigned short* h2r = s_h2[p];
        unsigned short*       h2w = s_h2[1 - p];

        f32x4 acc[4][4];
        bf16x8 a[4];
        // layer0: acc = pre0 + h1 @ Whhl0^T (K=128); mt 0,1 from AGPR, 2,3 from LDS
#pragma unroll
        for (int mt = 0; mt < 2; ++mt)
#pragma unroll
            for (int G = 0; G < 4; ++G) acc[mt][G] = pre0[mt][G];
#pragma unroll
        for (int q = 0; q < 2; ++q)
#pragma unroll
            for (int G = 0; G < 4; ++G)
                acc[2 + q][G] = s_pre[(q * 4 + G) * 512 + tid];
        LOAD_A(h1r, 0); MFMA_G(0); LOAD_B(0, pkL0, 4, 2);
        LOAD_A(h1r, 1); MFMA_G(1); LOAD_B(1, pkL0, 4, 3);
        LOAD_A(h1r, 2); MFMA_G(0); LOAD_B(0, pkL1, 8, 0);
        LOAD_A(h1r, 3); MFMA_G(1); LOAD_B(1, pkL1, 8, 1);
        // pointwise layer0 (loads for L1 k0/k1 in flight, covered by this + barrier)
#pragma unroll
        for (int mt = 0; mt < 4; ++mt)
#pragma unroll
            for (int r = 0; r < 4; ++r) {
                float iv = acc[mt][0][r], fv = acc[mt][1][r], gv = acc[mt][2][r], ov = acc[mt][3][r];
                float cn = sigf(fv) * c1v[mt][r] + sigf(iv) * tanhf_(gv);
                float hn = sigf(ov) * tanhf_(cn);
                c1v[mt][r] = cn;
                int ml = mt * 16 + quad * 4 + r;
                h1w[ml * 128 + ((((w * 2) + (nq >> 3)) ^ (quad * 4 + r)) << 3) + (nq & 7)] = f2bf(hn);
            }
        __syncthreads();   // B1: new h1 visible
        // layer1: acc = bl1 + [h1_new | h2] @ [Wihl1 | Whhl1]^T  (K=256)
#pragma unroll
        for (int mt = 0; mt < 4; ++mt)
#pragma unroll
            for (int G = 0; G < 4; ++G)
                acc[mt][G] = (f32x4){bl1[G], bl1[G], bl1[G], bl1[G]};
        LOAD_A(h1w, 0); MFMA_G(0); LOAD_B(0, pkL1, 8, 2);
        LOAD_A(h1w, 1); MFMA_G(1); LOAD_B(1, pkL1, 8, 3);
        LOAD_A(h1w, 2); MFMA_G(0); LOAD_B(0, pkL1, 8, 4);
        LOAD_A(h1w, 3); MFMA_G(1); LOAD_B(1, pkL1, 8, 5);
        LOAD_A(h2r, 0); MFMA_G(0); LOAD_B(0, pkL1, 8, 6);
        LOAD_A(h2r, 1); MFMA_G(1); LOAD_B(1, pkL1, 8, 7);
        LOAD_A(h2r, 2); MFMA_G(0); LOAD_B(0, pkL0, 4, 0);   // next step L0 k0
        LOAD_A(h2r, 3); MFMA_G(1); LOAD_B(1, pkL0, 4, 1);   // next step L0 k1
        // pointwise layer1 (next-step L0 loads in flight over pointwise+head+barrier)
#pragma unroll
        for (int mt = 0; mt < 4; ++mt)
#pragma unroll
            for (int r = 0; r < 4; ++r) {
                float iv = acc[mt][0][r], fv = acc[mt][1][r], gv = acc[mt][2][r], ov = acc[mt][3][r];
                float cn = sigf(fv) * c2v[mt][r] + sigf(iv) * tanhf_(gv);
                float hn = sigf(ov) * tanhf_(cn);
                c2v[mt][r] = cn;
                int ml = mt * 16 + quad * 4 + r;
                h2w[ml * 128 + ((((w * 2) + (nq >> 3)) ^ (quad * 4 + r)) << 3) + (nq & 7)] = f2bf(hn);
            }
        __syncthreads();   // B2: new h2 visible
        // output head: out[m, s, :] = h2_new @ Wout^T + bout, spread over all
        // 512 threads: tid -> (ml = tid>>3, oc = bit2, kc = bits[1:0] -> 4 of 16
        // column chunks each), then reduce the 4 partials with shfl_xor.
        {
            int ml = tid >> 3;
            int kc = tid & 3;
            const float* wr = s_wo + ((tid >> 2) & 1) * 128;
            int mx = ml & 15;
            float sum = 0.f;
#pragma unroll
            for (int c4 = 0; c4 < 4; ++c4) {
                int c = kc * 4 + c4;
                bf16x8 hv = *(const bf16x8*)&h2w[ml * 128 + ((c ^ mx) << 3)];
                int k0 = c << 3;
#pragma unroll
                for (int j = 0; j < 8; ++j)
                    sum += bf2f((unsigned short)hv[j]) * wr[k0 + j];
            }
            sum += __shfl_xor(sum, 1);
            sum += __shfl_xor(sum, 2);
            if (kc == 0) s_out[ml * 24 + s * 2 + ((tid >> 2) & 1)] = sum + bo2;
        }
    }
    __syncthreads();
    // single contiguous coalesced store: 64 samples x 24 floats = 6 KB
    for (int i = tid; i < 1536; i += 512) out[m0 * 24 + i] = s_out[i];
}

extern "C" void kernel_launch(void* const* d_in, const int* in_sizes, int n_in,
                              void* d_out, int out_size, void* d_ws, size_t ws_size,
                              hipStream_t stream) {
    const float* fused  = (const float*)d_in[0];
    const float* intent = (const float*)d_in[1];
    const float* Winit  = (const float*)d_in[2];
    const float* binit  = (const float*)d_in[3];
    const float* Wihl0  = (const float*)d_in[4];
    const float* Whhl0  = (const float*)d_in[5];
    const float* bihl0  = (const float*)d_in[6];
    const float* bhhl0  = (const float*)d_in[7];
    const float* Wihl1  = (const float*)d_in[8];
    const float* Whhl1  = (const float*)d_in[9];
    const float* bihl1  = (const float*)d_in[10];
    const float* bhhl1  = (const float*)d_in[11];
    const float* Wout   = (const float*)d_in[12];
    const float* bout   = (const float*)d_in[13];
    int Bsz = in_sizes[0] / 128;

    unsigned short* pkw = (unsigned short*)d_ws;   // single 640 KB copy
    pack_w<<<1280, 256, 0, stream>>>(Winit, Wihl0, Whhl0, Wihl1, Whhl1, pkw, 1);
    traj_main<<<Bsz / 64, 512, 0, stream>>>(fused, intent, binit, Winit, Wihl0, bihl0,
                                            bhhl0, bihl1, bhhl1, Wout, bout, pkw,
                                            (float*)d_out, Bsz);
}

// Round 10
// 1879.794 us; speedup vs baseline: 1.6193x; 1.1022x over previous
//
#include <hip/hip_runtime.h>

#define SEQ 12

typedef __attribute__((ext_vector_type(8))) short bf16x8;   // 8 bf16 bit patterns (4 VGPRs)
typedef __attribute__((ext_vector_type(4))) float f32x4;
typedef __attribute__((ext_vector_type(4))) unsigned short us4;

__device__ __forceinline__ unsigned short f2bf(float x) {
    unsigned u = __builtin_bit_cast(unsigned, x);
    u += 0x7fffu + ((u >> 16) & 1u);            // round-to-nearest-even
    return (unsigned short)(u >> 16);
}
__device__ __forceinline__ float bf2f(unsigned short h) {
    unsigned u = ((unsigned)h) << 16;
    return __builtin_bit_cast(float, u);
}
// native-rate activations (r7): v_rcp_f32 + v_exp_f32, inf-safe at both tails.
__device__ __forceinline__ float sigf(float x) {
    return __builtin_amdgcn_rcpf(1.0f + __builtin_amdgcn_exp2f(-1.4426950408889634f * x));
}
__device__ __forceinline__ float tanhf_(float x) {
    return 1.0f - 2.0f * __builtin_amdgcn_rcpf(1.0f + __builtin_amdgcn_exp2f(2.8853900817779268f * x));
}

// ---------------- weight pack kernel (layout UNCHANGED) ----------------
// d_ws layout (ushort), SINGLE copy (640 KB):
//   [0,65536)        PRE0 = bf16(W_ih_l0[:, :128])  K=128
//   [65536,131072)   INIT = bf16(W_init [:, :128])  K=128
//   [131072,196608)   L0  = bf16(W_hh_l0)           K=128
//   [196608,327680)   L1  = bf16([W_ih_l1|W_hh_l1]) K=256
// fragment order: chunk = ((w*4+G)*KK + kk), within chunk: lane*8+j,
//   n = G*128 + w*16 + (lane&15),  k = kk*32 + (lane>>4)*8 + j
__global__ void pack_w(const float* __restrict__ Winit, const float* __restrict__ Wihl0,
                       const float* __restrict__ Whhl0, const float* __restrict__ Wihl1,
                       const float* __restrict__ Whhl1, unsigned short* __restrict__ pk,
                       int ncopy) {
    int id = blockIdx.x * 256 + threadIdx.x;
    if (id >= 327680) return;
    float v;
    if (id < 131072) {                       // PRE0 / INIT (stride 129, KK=4)
        int e = id & 65535;
        int c = e >> 9, r = e & 511;
        int lane = r >> 3, j = r & 7;
        int kk = c & 3, G = (c >> 2) & 3, w = c >> 4;
        int n = G * 128 + w * 16 + (lane & 15);
        int k = kk * 32 + (lane >> 4) * 8 + j;
        const float* W = (id >> 16) ? Winit : Wihl0;
        v = W[n * 129 + k];
    } else if (id < 196608) {                // L0 (stride 128, KK=4)
        int e = id - 131072;
        int c = e >> 9, r = e & 511;
        int lane = r >> 3, j = r & 7;
        int kk = c & 3, G = (c >> 2) & 3, w = c >> 4;
        int n = G * 128 + w * 16 + (lane & 15);
        int k = kk * 32 + (lane >> 4) * 8 + j;
        v = Whhl0[n * 128 + k];
    } else {                                 // L1 (K=256, KK=8)
        int e = id - 196608;
        int c = e >> 9, r = e & 511;
        int lane = r >> 3, j = r & 7;
        int kk = c & 7, G = (c >> 3) & 3, w = c >> 5;
        int n = G * 128 + w * 16 + (lane & 15);
        int k = kk * 32 + (lane >> 4) * 8 + j;
        v = (k < 128) ? Wihl1[n * 128 + k] : Whhl1[n * 128 + (k - 128)];
    }
    unsigned short hv = f2bf(v);
    for (int cpy = 0; cpy < ncopy; ++cpy) pk[cpy * 327680 + id] = hv;
}

// per-group helpers (macros so everything stays in registers, fully unrolled)
#define LOAD_A(hb, kkl) do { _Pragma("unroll") \
    for (int mt = 0; mt < 4; ++mt) \
        a[mt] = *(const bf16x8*)&(hb)[(mt * 16 + nq) * 128 + ((((kkl) * 4 + quad) ^ nq) << 3)]; \
    } while (0)
#define LOAD_B(slot, base, KK, kk) do { _Pragma("unroll") \
    for (int G = 0; G < 4; ++G) \
        bb[slot][G] = *(const bf16x8*)&(base)[((w * 4 + G) * (KK) + (kk)) * 512 + lane * 8]; \
    } while (0)
#define MFMA_G(slot) do { _Pragma("unroll") \
    for (int mt = 0; mt < 4; ++mt) { _Pragma("unroll") \
        for (int G = 0; G < 4; ++G) \
            acc[mt][G] = __builtin_amdgcn_mfma_f32_16x16x32_bf16(a[mt], bb[slot][G], acc[mt][G], 0, 0, 0); } \
    } while (0)

// ---------------- fused decoder kernel ----------------
// block: 512 thr (8 waves), Mt=64. wave w owns hidden cols [16w,16w+16) x 4 gates.
// Lineage: r6 weight prefetch ring; r7 native activations + distributed head;
// r9 single weight copy; r11 c-state bf16 in conflict-free LDS + pre0 mt3 LDS.
// r14: TWO-PASS PHASE A. Cross-round evidence says arch-VGPR pressure drives
// the persistent scratch spill (c regs->LDS cut WRITE 221MB, LDS->regs raised
// it 144MB; AGPR-only moves ~nothing), and the kernel-wide arch cap of 128 was
// set by PHASE A's peak AGPR demand (pre0 64 + acc2 64 live at once = 128).
// Splitting phase A into INIT pass then PRE0 pass (each 64 AGPR peak, operand
// transients halved) drops kernel AGPR peak to the loop's 112 -> arch budget
// 144, and removes the phase-A pressure spike that was itself a spill source.
// Loop body, c layout, macros, and all numerics are IDENTICAL to r11.
__global__ __launch_bounds__(512) __attribute__((amdgpu_waves_per_eu(2, 2)))
void traj_main(const float* __restrict__ fused, const float* __restrict__ intent,
               const float* __restrict__ binit,
               const float* __restrict__ Winit, const float* __restrict__ Wihl0,
               const float* __restrict__ bihl0, const float* __restrict__ bhhl0,
               const float* __restrict__ bihl1, const float* __restrict__ bhhl1,
               const float* __restrict__ Wout, const float* __restrict__ bout,
               const unsigned short* __restrict__ pk,
               float* __restrict__ out, int Bsz) {
    // phase-A x-tiles union c1+c2 loop storage (x dead after PRE0 pass)
    __shared__ __align__(16) unsigned char s_u[32768];
    unsigned short* s_x  = (unsigned short*)s_u;            // 64x128 bf16 (16 KB)
    unsigned short* s_xi = (unsigned short*)(s_u + 16384);  // 64x128 bf16 (16 KB)
    unsigned short* s_c1 = (unsigned short*)s_u;            // [4][512][4] bf16 (16 KB)
    unsigned short* s_c2 = (unsigned short*)(s_u + 16384);  // [4][512][4] bf16 (16 KB)
    __shared__ __align__(16) float s_pre[4 * 512 * 4];      // pre0 mt=3: [G][tid][r] f32 (32 KB)
    __shared__ __align__(16) unsigned short s_h1[2][64 * 128];   // h1 dbuf ([1] = c1 staging pre-loop)
    __shared__ __align__(16) unsigned short s_h2[2][64 * 128];   // h2 dbuf ([1] = c2 staging pre-loop)
    __shared__ float s_wo[256];                                  // W_out (2x128)
    __shared__ float s_out[64 * 24];                             // per-step outputs

    const int tid = threadIdx.x;
    const int lane = tid & 63;
    const int w = tid >> 6;          // wave 0..7
    const int nq = lane & 15;
    const int quad = lane >> 4;
    const int m0 = blockIdx.x * 64;
    const int Bh = Bsz >> 1;

    const unsigned short* pkPRE = pk;
    const unsigned short* pkINI = pk + 65536;
    const unsigned short* pkL0  = pk + 131072;
    const unsigned short* pkL1  = pk + 196608;

    if (tid < 256) s_wo[tid] = Wout[tid];
    const float bo2 = bout[(tid >> 2) & 1];    // head: oc = bit2 of tid

    // per-lane column constants (n = G*128 + 16w + nq)
    float bpre[4], bl1[4], wcp[4], wci[4], bini[4];
#pragma unroll
    for (int G = 0; G < 4; ++G) {
        int n = G * 128 + w * 16 + nq;
        bpre[G] = bihl0[n] + bhhl0[n];
        bl1[G]  = bihl1[n] + bhhl1[n];
        wcp[G]  = Wihl0[n * 129 + 128];    // intent column of W_ih_l0
        wci[G]  = Winit[n * 129 + 128];    // intent column of W_init
        bini[G] = binit[n];
    }

    // ---- stage tiles as bf16 (swizzled A-layout)
#pragma unroll
    for (int it = 0; it < 8; ++it) {
        int f = it * 512 + tid;
        int row = f >> 5, fc = f & 31;
        int g = (row < 64) ? (m0 + row)
                           : ((row < 96) ? ((m0 >> 1) + (row - 64))
                                         : (Bh + (m0 >> 1) + (row - 96)));
        f32x4 v = *(const f32x4*)(fused + g * 128 + fc * 4);
        us4 u;
#pragma unroll
        for (int j = 0; j < 4; ++j) u[j] = f2bf(v[j]);
        int m = row & 63;
        int cp = (fc >> 1) ^ (m & 15);
        unsigned short* buf = (row < 64) ? s_x : s_xi;
        *(us4*)&buf[m * 128 + cp * 8 + (fc & 1) * 4] = u;
    }
    __syncthreads();

    // ======== phase A pass 1: INIT only (peak 64 AGPR) ========
    {
        f32x4 acc2[4][4];
#pragma unroll
        for (int mt = 0; mt < 4; ++mt)
#pragma unroll
            for (int G = 0; G < 4; ++G)
                acc2[mt][G] = (f32x4){0.f, 0.f, 0.f, 0.f};
#pragma unroll
        for (int kk = 0; kk < 4; ++kk) {
            bf16x8 a2[4], b2[4];
#pragma unroll
            for (int mt = 0; mt < 4; ++mt)
                a2[mt] = *(const bf16x8*)&s_xi[(mt * 16 + nq) * 128 + (((kk * 4 + quad) ^ nq) << 3)];
#pragma unroll
            for (int G = 0; G < 4; ++G)
                b2[G] = *(const bf16x8*)&pkINI[((w * 4 + G) * 4 + kk) * 512 + lane * 8];
#pragma unroll
            for (int mt = 0; mt < 4; ++mt)
#pragma unroll
                for (int G = 0; G < 4; ++G)
                    acc2[mt][G] = __builtin_amdgcn_mfma_f32_16x16x32_bf16(a2[mt], b2[G], acc2[mt][G], 0, 0, 0);
        }
#pragma unroll
        for (int mt = 0; mt < 4; ++mt)
#pragma unroll
            for (int r = 0; r < 4; ++r) {
                int ml = mt * 16 + quad * 4 + r;
                int grow = (mt < 2) ? ((m0 >> 1) + ml) : (Bh + (m0 >> 1) + (ml - 32));
                float iv2 = intent[grow];
#pragma unroll
                for (int G = 0; G < 4; ++G)
                    acc2[mt][G][r] += bini[G] + iv2 * wci[G];
            }
        // unpack init (torch-faithful flat reshape of [B,2H]->(2,B,H)):
        // G0/G1 -> h (swizzled bf16, s_h*[0]); G2/G3 -> c (linear bf16 staging
        // in s_h*[1], copied to loop layout after the PRE0 pass).
        int kq = w * 16 + nq, kc = kq >> 3, klo = kq & 7;
#pragma unroll
        for (int mt = 0; mt < 4; ++mt)
#pragma unroll
            for (int r = 0; r < 4; ++r) {
                int ri = mt * 16 + quad * 4 + r;
                int layer = mt >> 1;
                int ril = ri & 31;
#pragma unroll
                for (int G = 0; G < 4; ++G) {
                    int ml = 2 * ril + (G & 1);
                    unsigned short hv = f2bf(acc2[mt][G][r]);
                    if (G < 2) {
                        unsigned short* hb = layer ? s_h2[0] : s_h1[0];
                        hb[ml * 128 + ((kc ^ (ml & 15)) << 3) + klo] = hv;
                    } else {
                        unsigned short* cb = layer ? s_h2[1] : s_h1[1];
                        cb[ml * 128 + kq] = hv;
                    }
                }
            }
    }   // acc2 dead here

    // ======== phase A pass 2: PRE0 (peak 64 AGPR, acc2 retired) ========
    f32x4 pre0[3][4], pre3[4];
#pragma unroll
    for (int G = 0; G < 4; ++G) {
        pre3[G] = (f32x4){0.f, 0.f, 0.f, 0.f};
#pragma unroll
        for (int mt = 0; mt < 3; ++mt)
            pre0[mt][G] = (f32x4){0.f, 0.f, 0.f, 0.f};
    }
#pragma unroll
    for (int kk = 0; kk < 4; ++kk) {
        bf16x8 av[4], bv[4];
#pragma unroll
        for (int mt = 0; mt < 4; ++mt)
            av[mt] = *(const bf16x8*)&s_x[(mt * 16 + nq) * 128 + (((kk * 4 + quad) ^ nq) << 3)];
#pragma unroll
        for (int G = 0; G < 4; ++G)
            bv[G] = *(const bf16x8*)&pkPRE[((w * 4 + G) * 4 + kk) * 512 + lane * 8];
#pragma unroll
        for (int mt = 0; mt < 4; ++mt)
#pragma unroll
            for (int G = 0; G < 4; ++G) {
                f32x4& pd = (mt < 3) ? pre0[mt][G] : pre3[G];
                pd = __builtin_amdgcn_mfma_f32_16x16x32_bf16(av[mt], bv[G], pd, 0, 0, 0);
            }
    }
#pragma unroll
    for (int mt = 0; mt < 4; ++mt)
#pragma unroll
        for (int r = 0; r < 4; ++r) {
            int ml = mt * 16 + quad * 4 + r;
            float iv = intent[m0 + ml];
#pragma unroll
            for (int G = 0; G < 4; ++G) {
                f32x4& pd = (mt < 3) ? pre0[mt][G] : pre3[G];
                pd[r] += bpre[G] + iv * wcp[G];
            }
        }
    __syncthreads();   // all s_x/s_xi reads done; unpack h/c writes visible

    // ---- pre3 -> LDS (f32 exact); c staging -> conflict-free loop layout
#pragma unroll
    for (int G = 0; G < 4; ++G)
        *(f32x4*)&s_pre[G * 2048 + tid * 4] = pre3[G];
    {
        int kq = w * 16 + nq;
#pragma unroll
        for (int mt = 0; mt < 4; ++mt)
#pragma unroll
            for (int r = 0; r < 4; ++r) {
                int ml = mt * 16 + quad * 4 + r;
                s_c1[mt * 2048 + tid * 4 + r] = s_h1[1][ml * 128 + kq];
                s_c2[mt * 2048 + tid * 4 + r] = s_h2[1][ml * 128 + kq];
            }
    }
    __syncthreads();   // c copy done before step 0 overwrites s_h*[1]

    // ---- prefetch ring warm-up: first two weight groups of step 0
    bf16x8 bb[2][4];
    LOAD_B(0, pkL0, 4, 0);
    LOAD_B(1, pkL0, 4, 1);

    // ---- 12 decode steps; ring of 12 groups/step: L0 k0..3, L1 k0..7.
    // pattern per group: MFMA(slot) then refill same slot with group 2 ahead.
#pragma unroll 1
    for (int s = 0; s < SEQ; ++s) {
        const int p = s & 1;
        const unsigned short* h1r = s_h1[p];
        unsigned short*       h1w = s_h1[1 - p];
        const unsigned short* h2r = s_h2[p];
        unsigned short*       h2w = s_h2[1 - p];

        f32x4 acc[4][4];
        bf16x8 a[4];
        // layer0: acc = pre0 + h1 @ Whhl0^T (K=128); mt 0-2 from AGPR, mt3 from LDS
#pragma unroll
        for (int mt = 0; mt < 3; ++mt)
#pragma unroll
            for (int G = 0; G < 4; ++G) acc[mt][G] = pre0[mt][G];
#pragma unroll
        for (int G = 0; G < 4; ++G)
            acc[3][G] = *(const f32x4*)&s_pre[G * 2048 + tid * 4];
        LOAD_A(h1r, 0); MFMA_G(0); LOAD_B(0, pkL0, 4, 2);
        LOAD_A(h1r, 1); MFMA_G(1); LOAD_B(1, pkL0, 4, 3);
        LOAD_A(h1r, 2); MFMA_G(0); LOAD_B(0, pkL1, 8, 0);
        LOAD_A(h1r, 3); MFMA_G(1); LOAD_B(1, pkL1, 8, 1);
        // pointwise layer0 (loads for L1 k0/k1 in flight, covered by this + barrier)
#pragma unroll
        for (int mt = 0; mt < 4; ++mt) {
            us4 ch = *(const us4*)&s_c1[mt * 2048 + tid * 4];
#pragma unroll
            for (int r = 0; r < 4; ++r) {
                float iv = acc[mt][0][r], fv = acc[mt][1][r], gv = acc[mt][2][r], ov = acc[mt][3][r];
                float cn = sigf(fv) * bf2f(ch[r]) + sigf(iv) * tanhf_(gv);
                float hn = sigf(ov) * tanhf_(cn);
                ch[r] = f2bf(cn);
                int ml = mt * 16 + quad * 4 + r;
                h1w[ml * 128 + ((((w * 2) + (nq >> 3)) ^ (quad * 4 + r)) << 3) + (nq & 7)] = f2bf(hn);
            }
            *(us4*)&s_c1[mt * 2048 + tid * 4] = ch;
        }
        __syncthreads();   // B1: new h1 visible
        // layer1: acc = bl1 + [h1_new | h2] @ [Wihl1 | Whhl1]^T  (K=256)
#pragma unroll
        for (int mt = 0; mt < 4; ++mt)
#pragma unroll
            for (int G = 0; G < 4; ++G)
                acc[mt][G] = (f32x4){bl1[G], bl1[G], bl1[G], bl1[G]};
        LOAD_A(h1w, 0); MFMA_G(0); LOAD_B(0, pkL1, 8, 2);
        LOAD_A(h1w, 1); MFMA_G(1); LOAD_B(1, pkL1, 8, 3);
        LOAD_A(h1w, 2); MFMA_G(0); LOAD_B(0, pkL1, 8, 4);
        LOAD_A(h1w, 3); MFMA_G(1); LOAD_B(1, pkL1, 8, 5);
        LOAD_A(h2r, 0); MFMA_G(0); LOAD_B(0, pkL1, 8, 6);
        LOAD_A(h2r, 1); MFMA_G(1); LOAD_B(1, pkL1, 8, 7);
        LOAD_A(h2r, 2); MFMA_G(0); LOAD_B(0, pkL0, 4, 0);   // next step L0 k0
        LOAD_A(h2r, 3); MFMA_G(1); LOAD_B(1, pkL0, 4, 1);   // next step L0 k1
        // pointwise layer1 (next-step L0 loads in flight over pointwise+head+barrier)
#pragma unroll
        for (int mt = 0; mt < 4; ++mt) {
            us4 ch = *(const us4*)&s_c2[mt * 2048 + tid * 4];
#pragma unroll
            for (int r = 0; r < 4; ++r) {
                float iv = acc[mt][0][r], fv = acc[mt][1][r], gv = acc[mt][2][r], ov = acc[mt][3][r];
                float cn = sigf(fv) * bf2f(ch[r]) + sigf(iv) * tanhf_(gv);
                float hn = sigf(ov) * tanhf_(cn);
                ch[r] = f2bf(cn);
                int ml = mt * 16 + quad * 4 + r;
                h2w[ml * 128 + ((((w * 2) + (nq >> 3)) ^ (quad * 4 + r)) << 3) + (nq & 7)] = f2bf(hn);
            }
            *(us4*)&s_c2[mt * 2048 + tid * 4] = ch;
        }
        __syncthreads();   // B2: new h2 visible
        // output head: out[m, s, :] = h2_new @ Wout^T + bout, spread over all
        // 512 threads: tid -> (ml = tid>>3, oc = bit2, kc = bits[1:0] -> 4 of 16
        // column chunks each), then reduce the 4 partials with shfl_xor.
        {
            int ml = tid >> 3;
            int kc = tid & 3;
            const float* wr = s_wo + ((tid >> 2) & 1) * 128;
            int mx = ml & 15;
            float sum = 0.f;
#pragma unroll
            for (int c4 = 0; c4 < 4; ++c4) {
                int c = kc * 4 + c4;
                bf16x8 hv = *(const bf16x8*)&h2w[ml * 128 + ((c ^ mx) << 3)];
                int k0 = c << 3;
#pragma unroll
                for (int j = 0; j < 8; ++j)
                    sum += bf2f((unsigned short)hv[j]) * wr[k0 + j];
            }
            sum += __shfl_xor(sum, 1);
            sum += __shfl_xor(sum, 2);
            if (kc == 0) s_out[ml * 24 + s * 2 + ((tid >> 2) & 1)] = sum + bo2;
        }
    }
    __syncthreads();
    // single contiguous coalesced store: 64 samples x 24 floats = 6 KB
    for (int i = tid; i < 1536; i += 512) out[m0 * 24 + i] = s_out[i];
}

extern "C" void kernel_launch(void* const* d_in, const int* in_sizes, int n_in,
                              void* d_out, int out_size, void* d_ws, size_t ws_size,
                              hipStream_t stream) {
    const float* fused  = (const float*)d_in[0];
    const float* intent = (const float*)d_in[1];
    const float* Winit  = (const float*)d_in[2];
    const float* binit  = (const float*)d_in[3];
    const float* Wihl0  = (const float*)d_in[4];
    const float* Whhl0  = (const float*)d_in[5];
    const float* bihl0  = (const float*)d_in[6];
    const float* bhhl0  = (const float*)d_in[7];
    const float* Wihl1  = (const float*)d_in[8];
    const float* Whhl1  = (const float*)d_in[9];
    const float* bihl1  = (const float*)d_in[10];
    const float* bhhl1  = (const float*)d_in[11];
    const float* Wout   = (const float*)d_in[12];
    const float* bout   = (const float*)d_in[13];
    int Bsz = in_sizes[0] / 128;

    unsigned short* pkw = (unsigned short*)d_ws;   // single 640 KB copy
    pack_w<<<1280, 256, 0, stream>>>(Winit, Wihl0, Whhl0, Wihl1, Whhl1, pkw, 1);
    traj_main<<<Bsz / 64, 512, 0, stream>>>(fused, intent, binit, Winit, Wihl0, bihl0,
                                            bhhl0, bihl1, bhhl1, Wout, bout, pkw,
                                            (float*)d_out, Bsz);
}